// Round 18
// baseline (336.233 us; speedup 1.0000x reference)
//
#include <hip/hip_runtime.h>
#include <hip/hip_bf16.h>

typedef __attribute__((ext_vector_type(8))) short short8;
typedef __attribute__((ext_vector_type(4))) float f32x4;

#define B_ 8
#define C_ 64
#define H_ 256
#define W_ 256
#define HW_ 65536
#define K_ 10
#define NS1 24
#define NS2 18
#define HP_ 258
#define WP_ 258
#define PXP_ (HP_*WP_)
#define SLABW 34
#define SLABR 6

// k_pre grid partition
#define NB_COMBINE 2692
#define NB_BORDER  514
#define NB_PREP    8192

static __device__ __forceinline__ unsigned short f2bf(float f) {
    __hip_bfloat16 hb = __float2bfloat16(f);
    return *(unsigned short*)&hb;
}
static __device__ __forceinline__ float bf2f(unsigned short u) {
    unsigned v = ((unsigned)u) << 16;
    float f;
    __builtin_memcpy(&f, &v, 4);
    return f;
}

// async global->LDS 16B (dest = wave-uniform base + lane*16, linear in tau)
static __device__ __forceinline__ void gload_lds16(const void* g, void* l) {
    __builtin_amdgcn_global_load_lds(
        (const __attribute__((address_space(1))) unsigned int*)(unsigned long long)g,
        (__attribute__((address_space(3))) unsigned int*)(unsigned int)(unsigned long long)l,
        16, 0, 0);
}

// iteration-order maps: dw outer in order {0,2,1} so the LAST dw-group (dw=1)
// leaves the center-tap A-frags cached for the par-expert steps.
__device__ __host__ constexpr int SDW(int ii) {
    return (ii / 6 == 0) ? 0 : ((ii / 6 == 1) ? 2 : 1);
}
__device__ __host__ constexpr int SDH(int ii) { return (ii % 6) / 2; }
__device__ __host__ constexpr int SH(int ii)  { return ii & 1; }
__device__ __host__ constexpr int SS(int ii)  {
    return ii < 18 ? (3 * SDH(ii) + SDW(ii)) * 2 + SH(ii) : ii;
}

// ---------------------------------------------------------------------------
// Merged pre-pass: combine + border-zero + prep (unchanged from R17).
// ---------------------------------------------------------------------------
__global__ __launch_bounds__(256) void k_pre(
    const float* __restrict__ x,
    const float* __restrict__ attn, const float* __restrict__ gamma,
    const float* __restrict__ w1, const float* __restrict__ b1,
    const float* __restrict__ w2, const float* __restrict__ b2,
    const float* __restrict__ w16, const float* __restrict__ w168,
    const float* __restrict__ w88,
    unsigned short* __restrict__ W4_1, unsigned short* __restrict__ W4_2,
    float* __restrict__ bias1, float* __restrict__ bias2,
    unsigned short* __restrict__ X1p, unsigned short* __restrict__ Tp)
{
    __shared__ float ls[64][65];
    const int bx = blockIdx.x;
    const int t = threadIdx.x;

    if (bx < NB_COMBINE) {
        const int N1 = B_ * NS1 * 2048;
        const int N2 = B_ * NS2 * 2048;
        int gid = bx * 256 + t;
        if (gid < N1) {
            int b = gid / (NS1 * 2048);
            int r = gid - b * (NS1 * 2048);
            int s = r >> 11;
            int r2 = r & 2047;
            int of = r2 >> 9, l = (r2 >> 3) & 63, j = r2 & 7;
            int o = of * 16 + (l & 15);
            int g = l >> 4;
            float val;
            if (s < 18) {
                int tp = s >> 1, h = s & 1;
                int c = h * 32 + g * 8 + j;
                float acc = 0.f;
                #pragma unroll
                for (int k = 0; k < K_; ++k)
                    acc += attn[b * K_ + k] * w2[((size_t)(k * 64 + o) * 64 + c) * 9 + tp];
                val = acc * gamma[b * 64 + o];
            } else {
                int e = s - 18;
                int m = e >> 1, h = e & 1;
                int c = h * 32 + g * 8 + j;
                const float* wm = (m == 0) ? w16 : (m == 1 ? w168 : w88);
                val = wm[o * 64 + c];
            }
            W4_1[gid] = f2bf(val);
        } else if (gid < N1 + N2) {
            int gid2 = gid - N1;
            int b = gid2 / (NS2 * 2048);
            int r = gid2 - b * (NS2 * 2048);
            int s = r >> 11;
            int r2 = r & 2047;
            int of = r2 >> 9, l = (r2 >> 3) & 63, j = r2 & 7;
            int o = of * 16 + (l & 15);
            int g = l >> 4;
            int tp = s >> 1, h = s & 1;
            int c = h * 32 + g * 8 + j;
            float acc = 0.f;
            #pragma unroll
            for (int k = 0; k < K_; ++k)
                acc += attn[b * K_ + k] * w1[((size_t)(k * 64 + o) * 64 + c) * 9 + tp];
            W4_2[gid2] = f2bf(acc * gamma[b * 64 + o]);
        } else if (gid < N1 + N2 + 1024) {
            int id2 = gid - N1 - N2;
            int b = id2 >> 7;
            int rest = id2 & 127;
            int o = rest >> 1;
            int which = rest & 1;
            const float* bb = which ? b1 : b2;
            float acc = 0.f;
            #pragma unroll
            for (int k = 0; k < K_; ++k) acc += attn[b * K_ + k] * bb[k * 64 + o];
            float v = acc * gamma[b * 64 + o];
            if (which) bias2[b * 64 + o] = v; else bias1[b * 64 + o] = v;
        }
    } else if (bx < NB_COMBINE + NB_BORDER) {
        int gid = (bx - NB_COMBINE) * 256 + t;
        if (gid >= 2 * B_ * 1028 * 8) return;
        int chunk = gid & 7;
        int rest = gid >> 3;
        int p = rest % 1028;
        int rb = rest / 1028;
        int buf = rb & 1, b = rb >> 1;
        int row, col;
        if (p < 258) { row = 0; col = p; }
        else if (p < 516) { row = 257; col = p - 258; }
        else if (p < 772) { row = p - 516 + 1; col = 0; }
        else { row = p - 772 + 1; col = 257; }
        unsigned short* base = (buf ? Tp : X1p) +
            ((size_t)b * PXP_ + (size_t)row * WP_ + col) * 64 + chunk * 8;
        *(short8*)base = (short8){0, 0, 0, 0, 0, 0, 0, 0};
    } else {
        int pb = bx - (NB_COMBINE + NB_BORDER);
        const int b = pb >> 10;
        const int px0 = (pb & 1023) * 64;
        const int row = px0 >> 8;
        const int col0 = px0 & 255;
        #pragma unroll
        for (int it = 0; it < 4; ++it) {
            int e = t + it * 256;
            int ch = e >> 4, q = e & 15;
            f32x4 v = *(const f32x4*)(x + ((size_t)(b * 64 + ch)) * HW_ + px0 + q * 4);
            ls[ch][q * 4 + 0] = v[0];
            ls[ch][q * 4 + 1] = v[1];
            ls[ch][q * 4 + 2] = v[2];
            ls[ch][q * 4 + 3] = v[3];
        }
        __syncthreads();
        unsigned short* dst = X1p + ((size_t)b * PXP_ + (size_t)(row + 1) * WP_ + col0 + 1) * 64;
        #pragma unroll
        for (int k = 0; k < 2; ++k) {
            int c = t + k * 256;
            int px = c >> 3, ch0 = (c & 7) * 8;
            short8 v8;
            #pragma unroll
            for (int j = 0; j < 8; ++j) v8[j] = (short)f2bf(ls[ch0 + j][px]);
            *(short8*)(dst + (size_t)px * 64 + ch0) = v8;
        }
    }
}

// ---------------------------------------------------------------------------
// PERSISTENT implicit-GEMM conv3x3 via MFMA 16x16x32 (R16 inner structure).
// Block: 128 thr / 2 waves; processes 4 consecutive w-tiles (4 rows x 32 px
// x 64 o each). After each tile's K-loop (lgkmcnt-only barrier, vmcnt NOT
// drained) the NEXT tile's par/slab/B0/B1 gloads are issued, then the current
// epilogue runs -> staging overlaps epilogue + fence instead of stalling the
// whole block. Conv1's T-line assembly moved to a 4KB ring-slot-2 alias
// (4 row-passes) so the slab is free for prefetch. LDS 38.4 KB, 4 blocks/CU.
// ---------------------------------------------------------------------------
template<int STAGE>
__global__ __launch_bounds__(128, 2) void k_conv(
    const unsigned short* __restrict__ Xp,    // A source [b][258][258][64] bf16 padded
    const unsigned short* __restrict__ Xres,  // stage2 residual (X1p, bf16 padded)
    const float* __restrict__ par,            // stage1 [b][3][HW]
    const unsigned short* __restrict__ W4,    // [b][NS][4][64][8] bf16
    const float* __restrict__ bias,           // [b][64]
    unsigned short* __restrict__ Tp,          // stage1 out [b][258][258][64] bf16
    float* __restrict__ Fout)                 // stage2 out [b][64][HW] f32
{
    constexpr int NS = (STAGE == 1) ? NS1 : NS2;
    __shared__ short xs[SLABR * SLABW * 64];  // 26112 B A-slab
    __shared__ short bring[3 * 2048];         // 12288 B B-ring (3 x 4KB)

    const int tid = threadIdx.x;
    const int l = tid & 63;
    const int wv = tid >> 6;                  // 0..1; wave owns rows 2wv, 2wv+1
    const int b = blockIdx.y;
    // XCD-aware bijective swizzle (128 blocks = 8 XCD x 16)
    const int bswz = (blockIdx.x & 7) * 16 + (blockIdx.x >> 3);
    const int rblk = bswz >> 1;               // 0..63
    const int cpair = bswz & 1;               // 0..1 (4 w-tiles each)
    const int gh0 = rblk * 4;
    const int ln15 = l & 15, g = l >> 4;

    const char* XbP = (const char*)Xp + (size_t)b * PXP_ * 128;
    const unsigned short* Wb = W4 + (size_t)b * (NS * 2048);

    float pvv[3][4];
    auto issue_par = [&](int w0n) {
        #pragma unroll
        for (int m = 0; m < 3; ++m)
            #pragma unroll
            for (int mf = 0; mf < 4; ++mf)
                pvv[m][mf] = par[((size_t)b * 3 + m) * HW_ +
                                 (gh0 + 2 * wv + (mf >> 1)) * W_ + w0n + 16 * (mf & 1) + ln15];
    };
    auto issue_slab = [&](int w0n) {
        #pragma unroll
        for (int it = 0; it < 13; ++it) {
            int tau = tid + it * 128;
            if (tau < SLABR * SLABW * 8) {
                int slot = tau & 7;
                int rest = tau >> 3;
                int px = rest % SLABW;
                int row = rest / SLABW;
                int cb = slot ^ (px & 7);
                gload_lds16(XbP + ((size_t)(gh0 + row) * WP_ + (w0n + px)) * 128 + cb * 16,
                            (char*)xs + (size_t)tau * 16);
            }
        }
    };
    auto stage_b = [&](int ii) {
        const char* src = (const char*)Wb + (size_t)SS(ii) * 4096;
        char* dst = (char*)bring + (ii % 3) * 4096;
        gload_lds16(src + tid * 16, dst + tid * 16);
        gload_lds16(src + 2048 + tid * 16, dst + 2048 + tid * 16);
    };
    auto ldA = [&](int ro, int ph, int hh, int dw) -> short8 {
        int idx = 16 * ph + ln15 + dw;
        int rowx = 2 * wv + ro;
        return *(const short8*)((const char*)xs + (rowx * SLABW + idx) * 128 +
                                ((((hh << 2) | g) ^ (idx & 7)) << 4));
    };

    // ---- prologue: issue tile-0 staging (par oldest, then slab, then B0,B1)
    {
        const int w00 = cpair * 128;
        if constexpr (STAGE == 1) issue_par(w00);
        issue_slab(w00);
        stage_b(0);
        stage_b(1);
    }

    #pragma unroll 1
    for (int t = 0; t < 4; ++t) {
        const int w0cur = cpair * 128 + t * 32;

        // pre-K fence: everything but the 2 newest (B1 stage) landed
        asm volatile("s_waitcnt vmcnt(2)" ::: "memory");
        __builtin_amdgcn_s_barrier();

        f32x4 acc[4][4];
        #pragma unroll
        for (int mf = 0; mf < 4; ++mf)
            #pragma unroll
            for (int of = 0; of < 4; ++of)
                acc[mf][of] = (f32x4){0.f, 0.f, 0.f, 0.f};

        short8 ca[4][2][2];   // [row-offset][px-half][K-half] - static idx

        #pragma unroll
        for (int ii = 0; ii < 18; ++ii) {
            const int dw = SDW(ii), dh = SDH(ii), hh = SH(ii);
            if (ii + 2 < NS) stage_b(ii + 2);
            const char* rb = (const char*)bring + (ii % 3) * 4096 + (size_t)l * 16;
            short8 bf0 = *(const short8*)(rb);
            short8 bf1 = *(const short8*)(rb + 1024);
            short8 bf2 = *(const short8*)(rb + 2048);
            short8 bf3 = *(const short8*)(rb + 3072);
            if (dh == 0) {
                ca[0][0][hh] = ldA(0, 0, hh, dw);
                ca[0][1][hh] = ldA(0, 1, hh, dw);
                ca[1][0][hh] = ldA(1, 0, hh, dw);
                ca[1][1][hh] = ldA(1, 1, hh, dw);
            } else {
                ca[dh + 1][0][hh] = ldA(dh + 1, 0, hh, dw);
                ca[dh + 1][1][hh] = ldA(dh + 1, 1, hh, dw);
            }
            __builtin_amdgcn_s_setprio(1);
            #pragma unroll
            for (int mf = 0; mf < 4; ++mf) {
                short8 a = ca[(mf >> 1) + dh][mf & 1][hh];
                acc[mf][0] = __builtin_amdgcn_mfma_f32_16x16x32_bf16(a, bf0, acc[mf][0], 0, 0, 0);
                acc[mf][1] = __builtin_amdgcn_mfma_f32_16x16x32_bf16(a, bf1, acc[mf][1], 0, 0, 0);
                acc[mf][2] = __builtin_amdgcn_mfma_f32_16x16x32_bf16(a, bf2, acc[mf][2], 0, 0, 0);
                acc[mf][3] = __builtin_amdgcn_mfma_f32_16x16x32_bf16(a, bf3, acc[mf][3], 0, 0, 0);
            }
            __builtin_amdgcn_s_setprio(0);
            if (ii + 1 < NS) {
                if (ii + 2 < NS) asm volatile("s_waitcnt vmcnt(2)" ::: "memory");
                else             asm volatile("s_waitcnt vmcnt(0)" ::: "memory");
                __builtin_amdgcn_s_barrier();
            }
        }

        if constexpr (STAGE == 1) {
            // par-expert steps: center-tap frags still cached in ca (loop ended dw=1)
            #pragma unroll
            for (int ii = 18; ii < 24; ++ii) {
                const int e = ii - 18, m = e >> 1, hh = e & 1;
                if (ii + 2 < NS1) stage_b(ii + 2);
                const char* rb = (const char*)bring + (ii % 3) * 4096 + (size_t)l * 16;
                short8 bf0 = *(const short8*)(rb);
                short8 bf1 = *(const short8*)(rb + 1024);
                short8 bf2 = *(const short8*)(rb + 2048);
                short8 bf3 = *(const short8*)(rb + 3072);
                short8 sa[4];
                #pragma unroll
                for (int mf = 0; mf < 4; ++mf) {
                    short8 base = ca[(mf >> 1) + 1][mf & 1][hh];
                    #pragma unroll
                    for (int j = 0; j < 8; ++j)
                        sa[mf][j] = (short)f2bf(bf2f((unsigned short)base[j]) * pvv[m][mf]);
                }
                __builtin_amdgcn_s_setprio(1);
                #pragma unroll
                for (int mf = 0; mf < 4; ++mf) {
                    acc[mf][0] = __builtin_amdgcn_mfma_f32_16x16x32_bf16(sa[mf], bf0, acc[mf][0], 0, 0, 0);
                    acc[mf][1] = __builtin_amdgcn_mfma_f32_16x16x32_bf16(sa[mf], bf1, acc[mf][1], 0, 0, 0);
                    acc[mf][2] = __builtin_amdgcn_mfma_f32_16x16x32_bf16(sa[mf], bf2, acc[mf][2], 0, 0, 0);
                    acc[mf][3] = __builtin_amdgcn_mfma_f32_16x16x32_bf16(sa[mf], bf3, acc[mf][3], 0, 0, 0);
                }
                __builtin_amdgcn_s_setprio(0);
                if (ii + 1 < NS1) {
                    if (ii + 2 < NS1) asm volatile("s_waitcnt vmcnt(2)" ::: "memory");
                    else              asm volatile("s_waitcnt vmcnt(0)" ::: "memory");
                    __builtin_amdgcn_s_barrier();
                }
            }
        }

        // ---- post-K sync: all LDS reads of slab/ring done (vmcnt NOT drained)
        asm volatile("s_waitcnt lgkmcnt(0)" ::: "memory");
        __builtin_amdgcn_s_barrier();

        // ---- overlap: issue NEXT tile's staging before this tile's epilogue
        if (t < 3) {
            const int w0n = w0cur + 32;
            if constexpr (STAGE == 1) issue_par(w0n);
            issue_slab(w0n);
            stage_b(0);
            stage_b(1);
        }

        // ---- epilogue for tile t
        if constexpr (STAGE == 1) {
            // 4 row-passes through a 4KB ring-slot-2 alias (slots 0/1 hold
            // the prefetched B; slot 2 is dead until next tile's step 2).
            unsigned short* tl4 = (unsigned short*)bring + 2 * 2048;  // 4 KB
            #pragma unroll
            for (int r = 0; r < 4; ++r) {
                if (wv == (r >> 1)) {
                    #pragma unroll
                    for (int of = 0; of < 4; ++of) {
                        int o = of * 16 + ln15;
                        float bi = bias[b * 64 + o];
                        #pragma unroll
                        for (int mm = 0; mm < 2; ++mm) {
                            int mf = 2 * (r & 1) + mm;
                            #pragma unroll
                            for (int q = 0; q < 4; ++q) {
                                int px = 16 * (mf & 1) + 4 * g + q;
                                float v = fmaxf(acc[mf][of][q] + bi, 0.f);
                                tl4[px * 64 + (o ^ ((px & 7) << 3))] = f2bf(v);
                            }
                        }
                    }
                }
                asm volatile("s_waitcnt lgkmcnt(0)" ::: "memory");
                __builtin_amdgcn_s_barrier();
                #pragma unroll
                for (int it = 0; it < 2; ++it) {
                    int tau = tid + it * 128;
                    int px = tau >> 3;
                    int j = tau & 7;
                    short8 v = *(const short8*)(tl4 + px * 64 + ((j ^ (px & 7)) * 8));
                    *(short8*)(Tp + ((size_t)b * PXP_ + (size_t)(gh0 + r + 1) * WP_ +
                                     (w0cur + 1 + px)) * 64 + j * 8) = v;
                }
                asm volatile("s_waitcnt lgkmcnt(0)" ::: "memory");
                __builtin_amdgcn_s_barrier();
            }
        } else {
            const unsigned short* Xr = Xres + (size_t)b * PXP_ * 64;
            #pragma unroll
            for (int of = 0; of < 4; ++of) {
                int o = of * 16 + ln15;
                float bi = bias[b * 64 + o];
                #pragma unroll
                for (int mf = 0; mf < 4; ++mf) {
                    int gh = gh0 + 2 * wv + (mf >> 1);
                    int gw = w0cur + 16 * (mf & 1) + g * 4;
                    size_t idx = ((size_t)b * 64 + o) * HW_ + (size_t)gh * W_ + gw;
                    const unsigned short* xr =
                        Xr + ((size_t)(gh + 1) * WP_ + (gw + 1)) * 64 + o;
                    f32x4 ov;
                    #pragma unroll
                    for (int q = 0; q < 4; ++q)
                        ov[q] = bf2f(xr[(size_t)q * 64]) + acc[mf][of][q] + bi;
                    *(f32x4*)(Fout + idx) = ov;
                }
            }
        }
    }
}

extern "C" void kernel_launch(void* const* d_in, const int* in_sizes, int n_in,
                              void* d_out, int out_size, void* d_ws, size_t ws_size,
                              hipStream_t stream) {
    const float* x     = (const float*)d_in[0];
    const float* attn  = (const float*)d_in[1];
    const float* gamma = (const float*)d_in[2];
    const float* par   = (const float*)d_in[3];
    const float* w1    = (const float*)d_in[4];
    const float* b1    = (const float*)d_in[5];
    const float* w2    = (const float*)d_in[6];
    const float* b2    = (const float*)d_in[7];
    const float* w16   = (const float*)d_in[8];
    const float* w168  = (const float*)d_in[9];
    const float* w88   = (const float*)d_in[10];
    float* out = (float*)d_out;

    char* w = (char*)d_ws;
    unsigned short* W4_1 = (unsigned short*)w;                        // 786432 B
    unsigned short* W4_2 = (unsigned short*)(w + 786432);             // 589824 B
    float* bias1 = (float*)(w + 786432 + 589824);                     // 2048 B
    float* bias2 = (float*)(w + 786432 + 589824 + 2048);              // 2048 B
    unsigned short* X1p = (unsigned short*)(w + 1380352);             // 68161536 B
    unsigned short* Tp  = (unsigned short*)(w + 1380352 + 68161536);  // 68161536 B

    k_pre<<<dim3(NB_COMBINE + NB_BORDER + NB_PREP), dim3(256), 0, stream>>>(
        x, attn, gamma, w1, b1, w2, b2, w16, w168, w88,
        W4_1, W4_2, bias1, bias2, X1p, Tp);

    dim3 grid(128, 8);
    k_conv<1><<<grid, dim3(128), 0, stream>>>(X1p, nullptr, par, W4_1, bias1, Tp, nullptr);
    k_conv<2><<<grid, dim3(128), 0, stream>>>(Tp, X1p, par, W4_2, bias2, nullptr, out);
}

// Round 19
// 175.668 us; speedup vs baseline: 1.9140x; 1.9140x over previous
//
#include <hip/hip_runtime.h>
#include <hip/hip_bf16.h>

typedef __attribute__((ext_vector_type(8))) short short8;
typedef __attribute__((ext_vector_type(4))) float f32x4;

#define B_ 8
#define C_ 64
#define H_ 256
#define W_ 256
#define HW_ 65536
#define K_ 10
#define NS1 24
#define NS2 18
#define HP_ 258
#define WP_ 258
#define PXP_ (HP_*WP_)
#define SLABW 34
#define SLABR 6
#define HSLAB_B (SLABR*SLABW*64)     // 13056 B half-slab (32 ch)
#define RING_OFF HSLAB_B
#define LDS_TOT (HSLAB_B + 3*4096)   // 25344 B

// k_pre grid partition
#define NB_COMBINE 2692
#define NB_BORDER  514
#define NB_PREP    8192

static __device__ __forceinline__ unsigned short f2bf(float f) {
    __hip_bfloat16 hb = __float2bfloat16(f);
    return *(unsigned short*)&hb;
}
static __device__ __forceinline__ float bf2f(unsigned short u) {
    unsigned v = ((unsigned)u) << 16;
    float f;
    __builtin_memcpy(&f, &v, 4);
    return f;
}

// async global->LDS 16B (dest = wave-uniform base + lane*16, linear in tau)
static __device__ __forceinline__ void gload_lds16(const void* g, void* l) {
    __builtin_amdgcn_global_load_lds(
        (const __attribute__((address_space(1))) unsigned int*)(unsigned long long)g,
        (__attribute__((address_space(3))) unsigned int*)(unsigned int)(unsigned long long)l,
        16, 0, 0);
}

// per-pass tap order: dw outer {0,2,1} x dh {0,1,2}; ends at dw=1 so the
// center-tap A-frags stay cached for the par-expert steps.
__device__ __host__ constexpr int PDW(int jj) {
    return (jj / 3 == 0) ? 0 : ((jj / 3 == 1) ? 2 : 1);
}
__device__ __host__ constexpr int PDH(int jj) { return jj % 3; }
// W4 step index for pass h, pass-local step jj
__device__ __host__ constexpr int PS(int h, int jj) {
    return jj < 9 ? (PDH(jj) * 3 + PDW(jj)) * 2 + h : 18 + 2 * (jj - 9) + h;
}

// ---------------------------------------------------------------------------
// Merged pre-pass: combine + border-zero + prep (unchanged from R17).
// ---------------------------------------------------------------------------
__global__ __launch_bounds__(256) void k_pre(
    const float* __restrict__ x,
    const float* __restrict__ attn, const float* __restrict__ gamma,
    const float* __restrict__ w1, const float* __restrict__ b1,
    const float* __restrict__ w2, const float* __restrict__ b2,
    const float* __restrict__ w16, const float* __restrict__ w168,
    const float* __restrict__ w88,
    unsigned short* __restrict__ W4_1, unsigned short* __restrict__ W4_2,
    float* __restrict__ bias1, float* __restrict__ bias2,
    unsigned short* __restrict__ X1p, unsigned short* __restrict__ Tp)
{
    __shared__ float ls[64][65];
    const int bx = blockIdx.x;
    const int t = threadIdx.x;

    if (bx < NB_COMBINE) {
        const int N1 = B_ * NS1 * 2048;
        const int N2 = B_ * NS2 * 2048;
        int gid = bx * 256 + t;
        if (gid < N1) {
            int b = gid / (NS1 * 2048);
            int r = gid - b * (NS1 * 2048);
            int s = r >> 11;
            int r2 = r & 2047;
            int of = r2 >> 9, l = (r2 >> 3) & 63, j = r2 & 7;
            int o = of * 16 + (l & 15);
            int g = l >> 4;
            float val;
            if (s < 18) {
                int tp = s >> 1, h = s & 1;
                int c = h * 32 + g * 8 + j;
                float acc = 0.f;
                #pragma unroll
                for (int k = 0; k < K_; ++k)
                    acc += attn[b * K_ + k] * w2[((size_t)(k * 64 + o) * 64 + c) * 9 + tp];
                val = acc * gamma[b * 64 + o];
            } else {
                int e = s - 18;
                int m = e >> 1, h = e & 1;
                int c = h * 32 + g * 8 + j;
                const float* wm = (m == 0) ? w16 : (m == 1 ? w168 : w88);
                val = wm[o * 64 + c];
            }
            W4_1[gid] = f2bf(val);
        } else if (gid < N1 + N2) {
            int gid2 = gid - N1;
            int b = gid2 / (NS2 * 2048);
            int r = gid2 - b * (NS2 * 2048);
            int s = r >> 11;
            int r2 = r & 2047;
            int of = r2 >> 9, l = (r2 >> 3) & 63, j = r2 & 7;
            int o = of * 16 + (l & 15);
            int g = l >> 4;
            int tp = s >> 1, h = s & 1;
            int c = h * 32 + g * 8 + j;
            float acc = 0.f;
            #pragma unroll
            for (int k = 0; k < K_; ++k)
                acc += attn[b * K_ + k] * w1[((size_t)(k * 64 + o) * 64 + c) * 9 + tp];
            W4_2[gid2] = f2bf(acc * gamma[b * 64 + o]);
        } else if (gid < N1 + N2 + 1024) {
            int id2 = gid - N1 - N2;
            int b = id2 >> 7;
            int rest = id2 & 127;
            int o = rest >> 1;
            int which = rest & 1;
            const float* bb = which ? b1 : b2;
            float acc = 0.f;
            #pragma unroll
            for (int k = 0; k < K_; ++k) acc += attn[b * K_ + k] * bb[k * 64 + o];
            float v = acc * gamma[b * 64 + o];
            if (which) bias2[b * 64 + o] = v; else bias1[b * 64 + o] = v;
        }
    } else if (bx < NB_COMBINE + NB_BORDER) {
        int gid = (bx - NB_COMBINE) * 256 + t;
        if (gid >= 2 * B_ * 1028 * 8) return;
        int chunk = gid & 7;
        int rest = gid >> 3;
        int p = rest % 1028;
        int rb = rest / 1028;
        int buf = rb & 1, b = rb >> 1;
        int row, col;
        if (p < 258) { row = 0; col = p; }
        else if (p < 516) { row = 257; col = p - 258; }
        else if (p < 772) { row = p - 516 + 1; col = 0; }
        else { row = p - 772 + 1; col = 257; }
        unsigned short* base = (buf ? Tp : X1p) +
            ((size_t)b * PXP_ + (size_t)row * WP_ + col) * 64 + chunk * 8;
        *(short8*)base = (short8){0, 0, 0, 0, 0, 0, 0, 0};
    } else {
        int pb = bx - (NB_COMBINE + NB_BORDER);
        const int b = pb >> 10;
        const int px0 = (pb & 1023) * 64;
        const int row = px0 >> 8;
        const int col0 = px0 & 255;
        #pragma unroll
        for (int it = 0; it < 4; ++it) {
            int e = t + it * 256;
            int ch = e >> 4, q = e & 15;
            f32x4 v = *(const f32x4*)(x + ((size_t)(b * 64 + ch)) * HW_ + px0 + q * 4);
            ls[ch][q * 4 + 0] = v[0];
            ls[ch][q * 4 + 1] = v[1];
            ls[ch][q * 4 + 2] = v[2];
            ls[ch][q * 4 + 3] = v[3];
        }
        __syncthreads();
        unsigned short* dst = X1p + ((size_t)b * PXP_ + (size_t)(row + 1) * WP_ + col0 + 1) * 64;
        #pragma unroll
        for (int k = 0; k < 2; ++k) {
            int c = t + k * 256;
            int px = c >> 3, ch0 = (c & 7) * 8;
            short8 v8;
            #pragma unroll
            for (int j = 0; j < 8; ++j) v8[j] = (short)f2bf(ls[ch0 + j][px]);
            *(short8*)(dst + (size_t)px * 64 + ch0) = v8;
        }
    }
}

// ---------------------------------------------------------------------------
// Implicit-GEMM conv3x3 via MFMA 16x16x32, TWO ch-half passes over a
// HALF-SLAB [6][34][32ch] (13.1 KB). LDS total 25.3 KB -> 6 blocks/CU
// (12 waves/CU, 6 independent barrier domains; was 4/8 at 38.4 KB).
// Same per-step structure as R16/R17: dh-row caching (dw-outer order),
// B 3-slot x 4KB ring, distance-2 counted vmcnt, raw s_barrier, setprio.
// One full drain at the pass boundary (hidden by 5 other resident blocks).
// ---------------------------------------------------------------------------
template<int STAGE>
__global__ __launch_bounds__(128, 2) void k_conv(
    const unsigned short* __restrict__ Xp,    // A source [b][258][258][64] bf16 padded
    const unsigned short* __restrict__ Xres,  // stage2 residual (X1p, bf16 padded)
    const float* __restrict__ par,            // stage1 [b][3][HW]
    const unsigned short* __restrict__ W4,    // [b][NS][4][64][8] bf16
    const float* __restrict__ bias,           // [b][64]
    unsigned short* __restrict__ Tp,          // stage1 out [b][258][258][64] bf16
    float* __restrict__ Fout)                 // stage2 out [b][64][HW] f32
{
    constexpr int NP = (STAGE == 1) ? 12 : 9;   // steps per pass
    __shared__ char smem[LDS_TOT];
    short* xs = (short*)smem;                   // half-slab 13056 B
    char* bring = smem + RING_OFF;              // 12288 B B-ring

    const int tid = threadIdx.x;
    const int l = tid & 63;
    const int wv = tid >> 6;                  // 0..1; wave owns rows 2wv, 2wv+1
    const int b = blockIdx.y;
    // XCD-aware bijective swizzle (512 blocks = 8 XCD x 64)
    const int bswz = (blockIdx.x & 7) * 64 + (blockIdx.x >> 3);
    const int rblk = bswz >> 3;               // 0..63
    const int cblk = bswz & 7;                // 0..7
    const int gh0 = rblk * 4, w0 = cblk * 32;
    const int ln15 = l & 15, g = l >> 4;

    const char* XbP = (const char*)Xp + (size_t)b * PXP_ * 128;
    const unsigned short* Wb = W4 + (size_t)b * (((STAGE == 1) ? NS1 : NS2) * 2048);

    // par values (issued first so the prologue fence covers them)
    float pvv[3][4];
    if constexpr (STAGE == 1) {
        #pragma unroll
        for (int m = 0; m < 3; ++m)
            #pragma unroll
            for (int mf = 0; mf < 4; ++mf)
                pvv[m][mf] = par[((size_t)b * 3 + m) * HW_ +
                                 (gh0 + 2 * wv + (mf >> 1)) * W_ + w0 + 16 * (mf & 1) + ln15];
    }

    f32x4 acc[4][4];
    #pragma unroll
    for (int mf = 0; mf < 4; ++mf)
        #pragma unroll
        for (int of = 0; of < 4; ++of)
            acc[mf][of] = (f32x4){0.f, 0.f, 0.f, 0.f};

    // ---- half-slab stage for ch-half h: [6 rows][34 px][4 chunks of 16B]
    // bank swizzle chunk' = c ^ ((px>>1)&3); source carries the inverse.
    auto stage_slab = [&](int h) {
        #pragma unroll
        for (int it = 0; it < 7; ++it) {
            int tau = tid + it * 128;
            if (tau < SLABR * SLABW * 4) {
                int cs = tau & 3;
                int rest = tau >> 2;
                int px = rest % SLABW;
                int row = rest / SLABW;
                int c = cs ^ ((px >> 1) & 3);
                gload_lds16(XbP + ((size_t)(gh0 + row) * WP_ + (w0 + px)) * 128 +
                            (h * 4 + c) * 16,
                            (char*)xs + (size_t)tau * 16);
            }
        }
    };
    auto stage_b = [&](int h, int jj) {
        const char* src = (const char*)Wb + (size_t)PS(h, jj) * 4096;
        char* dst = bring + (jj % 3) * 4096;
        gload_lds16(src + tid * 16, dst + tid * 16);
        gload_lds16(src + 2048 + tid * 16, dst + 2048 + tid * 16);
    };
    // A-frag read from half-slab: row-offset ro, px-half ph, tap column dw
    auto ldA = [&](int ro, int ph, int dw) -> short8 {
        int idx = 16 * ph + ln15 + dw;
        int rowx = 2 * wv + ro;
        return *(const short8*)((const char*)xs +
                ((rowx * SLABW + idx) * 4 + (g ^ ((idx >> 1) & 3))) * 16);
    };

    #pragma unroll
    for (int h = 0; h < 2; ++h) {
        // ---- pass prologue: stage half-slab + B0,B1 (prior pass fully drained)
        stage_slab(h);
        stage_b(h, 0);
        stage_b(h, 1);
        asm volatile("s_waitcnt vmcnt(2)" ::: "memory");   // slab + B0 landed
        __builtin_amdgcn_s_barrier();

        short8 ca[4][2];   // [row-offset 0..3][px-half] - static idx, per pass

        #pragma unroll
        for (int jj = 0; jj < NP; ++jj) {
            if (jj + 2 < NP) stage_b(h, jj + 2);
            const char* rb = bring + (jj % 3) * 4096 + (size_t)l * 16;
            short8 bf0 = *(const short8*)(rb);
            short8 bf1 = *(const short8*)(rb + 1024);
            short8 bf2 = *(const short8*)(rb + 2048);
            short8 bf3 = *(const short8*)(rb + 3072);

            short8 a[4];
            if (jj < 9) {
                const int dw = PDW(jj), dh = PDH(jj);
                if (dh == 0) {
                    ca[0][0] = ldA(0, 0, dw);
                    ca[0][1] = ldA(0, 1, dw);
                    ca[1][0] = ldA(1, 0, dw);
                    ca[1][1] = ldA(1, 1, dw);
                } else {
                    ca[dh + 1][0] = ldA(dh + 1, 0, dw);
                    ca[dh + 1][1] = ldA(dh + 1, 1, dw);
                }
                #pragma unroll
                for (int mf = 0; mf < 4; ++mf) a[mf] = ca[(mf >> 1) + dh][mf & 1];
            } else {
                // par-expert steps: center-tap frags (dw=1, rows 1,2) cached
                const int m = jj - 9;
                #pragma unroll
                for (int mf = 0; mf < 4; ++mf) {
                    short8 base = ca[(mf >> 1) + 1][mf & 1];
                    #pragma unroll
                    for (int j = 0; j < 8; ++j)
                        a[mf][j] = (short)f2bf(bf2f((unsigned short)base[j]) * pvv[m][mf]);
                }
            }

            __builtin_amdgcn_s_setprio(1);
            #pragma unroll
            for (int mf = 0; mf < 4; ++mf) {
                acc[mf][0] = __builtin_amdgcn_mfma_f32_16x16x32_bf16(a[mf], bf0, acc[mf][0], 0, 0, 0);
                acc[mf][1] = __builtin_amdgcn_mfma_f32_16x16x32_bf16(a[mf], bf1, acc[mf][1], 0, 0, 0);
                acc[mf][2] = __builtin_amdgcn_mfma_f32_16x16x32_bf16(a[mf], bf2, acc[mf][2], 0, 0, 0);
                acc[mf][3] = __builtin_amdgcn_mfma_f32_16x16x32_bf16(a[mf], bf3, acc[mf][3], 0, 0, 0);
            }
            __builtin_amdgcn_s_setprio(0);

            if (jj + 1 < NP) {
                if (jj + 2 < NP) asm volatile("s_waitcnt vmcnt(2)" ::: "memory");
                else             asm volatile("s_waitcnt vmcnt(0)" ::: "memory");
                __builtin_amdgcn_s_barrier();
            }
        }
        // ---- pass boundary: full drain before slab overwrite / epilogue
        asm volatile("s_waitcnt vmcnt(0) lgkmcnt(0)" ::: "memory");
        __builtin_amdgcn_s_barrier();
    }

    if constexpr (STAGE == 1) {
        // ---- epilogue: assemble 128B lines in LDS (slab+ring alias), store x4
        unsigned short* tl = (unsigned short*)smem;   // 16 KB within 25.3 KB
        #pragma unroll
        for (int of = 0; of < 4; ++of) {
            int o = of * 16 + ln15;
            float bi = bias[b * 64 + o];
            #pragma unroll
            for (int mf = 0; mf < 4; ++mf) {
                int row_local = 2 * wv + (mf >> 1);
                #pragma unroll
                for (int q = 0; q < 4; ++q) {
                    int px = 16 * (mf & 1) + 4 * g + q;
                    float v = fmaxf(acc[mf][of][q] + bi, 0.f);
                    tl[row_local * 2048 + px * 64 + (o ^ ((px & 7) << 3))] = f2bf(v);
                }
            }
        }
        __syncthreads();
        #pragma unroll
        for (int it = 0; it < 8; ++it) {
            int tau = tid + it * 128;
            int row = tau >> 8;
            int px = (tau >> 3) & 31;
            int j = tau & 7;
            short8 v = *(const short8*)(tl + row * 2048 + px * 64 + ((j ^ (px & 7)) * 8));
            *(short8*)(Tp + ((size_t)b * PXP_ + (size_t)(gh0 + row + 1) * WP_ +
                             (w0 + 1 + px)) * 64 + j * 8) = v;
        }
    } else {
        // ---- epilogue: residual add from X1p (bf16, L3-hot) + f32x4 out
        const unsigned short* Xr = Xres + (size_t)b * PXP_ * 64;
        #pragma unroll
        for (int of = 0; of < 4; ++of) {
            int o = of * 16 + ln15;
            float bi = bias[b * 64 + o];
            #pragma unroll
            for (int mf = 0; mf < 4; ++mf) {
                int gh = gh0 + 2 * wv + (mf >> 1);
                int gw = w0 + 16 * (mf & 1) + g * 4;
                size_t idx = ((size_t)b * 64 + o) * HW_ + (size_t)gh * W_ + gw;
                const unsigned short* xr =
                    Xr + ((size_t)(gh + 1) * WP_ + (gw + 1)) * 64 + o;
                f32x4 ov;
                #pragma unroll
                for (int q = 0; q < 4; ++q)
                    ov[q] = bf2f(xr[(size_t)q * 64]) + acc[mf][of][q] + bi;
                *(f32x4*)(Fout + idx) = ov;
            }
        }
    }
}

extern "C" void kernel_launch(void* const* d_in, const int* in_sizes, int n_in,
                              void* d_out, int out_size, void* d_ws, size_t ws_size,
                              hipStream_t stream) {
    const float* x     = (const float*)d_in[0];
    const float* attn  = (const float*)d_in[1];
    const float* gamma = (const float*)d_in[2];
    const float* par   = (const float*)d_in[3];
    const float* w1    = (const float*)d_in[4];
    const float* b1    = (const float*)d_in[5];
    const float* w2    = (const float*)d_in[6];
    const float* b2    = (const float*)d_in[7];
    const float* w16   = (const float*)d_in[8];
    const float* w168  = (const float*)d_in[9];
    const float* w88   = (const float*)d_in[10];
    float* out = (float*)d_out;

    char* w = (char*)d_ws;
    unsigned short* W4_1 = (unsigned short*)w;                        // 786432 B
    unsigned short* W4_2 = (unsigned short*)(w + 786432);             // 589824 B
    float* bias1 = (float*)(w + 786432 + 589824);                     // 2048 B
    float* bias2 = (float*)(w + 786432 + 589824 + 2048);              // 2048 B
    unsigned short* X1p = (unsigned short*)(w + 1380352);             // 68161536 B
    unsigned short* Tp  = (unsigned short*)(w + 1380352 + 68161536);  // 68161536 B

    k_pre<<<dim3(NB_COMBINE + NB_BORDER + NB_PREP), dim3(256), 0, stream>>>(
        x, attn, gamma, w1, b1, w2, b2, w16, w168, w88,
        W4_1, W4_2, bias1, bias2, X1p, Tp);

    dim3 grid(512, 8);
    k_conv<1><<<grid, dim3(128), 0, stream>>>(X1p, nullptr, par, W4_1, bias1, Tp, nullptr);
    k_conv<2><<<grid, dim3(128), 0, stream>>>(Tp, X1p, par, W4_2, bias2, nullptr, out);
}